// Round 2
// baseline (7285.979 us; speedup 1.0000x reference)
//
#include <hip/hip_runtime.h>
#include <math.h>

#define Bsz 512
#define Hd 1024
#define Vd 512
#define TH3 3072
#define Cc 128
#define Ll 120
#define Kk 10
#define Oo 32
#define Tt 111      // L - K + 1
#define NSTEP 30

// ---------- conv_w [O,C,K] -> cwT [O,K,C] so inner c-loop is contiguous ----------
__global__ void k_twt(const float* __restrict__ cw, float* __restrict__ cwT) {
    int i = blockIdx.x * 256 + threadIdx.x;
    if (i < Oo * Cc * Kk) {
        int o = i / (Cc * Kk);
        int rem = i - o * (Cc * Kk);
        int c = rem / Kk;
        int k = rem - c * Kk;
        cwT[(o * Kk + k) * Cc + c] = cw[i];
    }
}

// ---------- conv1d (VALID, K=10) + bias + relu + max-over-time -> pooled [B,32] ----------
__global__ __launch_bounds__(256) void k_conv(const float* __restrict__ sm,
                                              const float* __restrict__ cwT,
                                              const float* __restrict__ cb,
                                              float* __restrict__ pooled) {
    __shared__ __align__(16) float xs[Ll * Cc];   // 60 KB: sm_hidden[b] as [L][C]
    __shared__ float red[8][33];
    int b = blockIdx.x, tid = threadIdx.x;
    const float4* src = (const float4*)(sm + (size_t)b * Ll * Cc);
    float4* dst = (float4*)xs;
    for (int i = tid; i < Ll * Cc / 4; i += 256) dst[i] = src[i];
    __syncthreads();
    int o = tid & 31, sub = tid >> 5;
    float bias = cb[o];
    float mx = 0.f;  // max over relu'd values == max(0, max over raw)
    for (int t = sub; t < Tt; t += 8) {
        float acc = bias;
        for (int k = 0; k < Kk; ++k) {
            const float4* xr = (const float4*)(xs + (t + k) * Cc);
            const float4* wr = (const float4*)(cwT + (o * Kk + k) * Cc);
#pragma unroll
            for (int c4 = 0; c4 < Cc / 4; ++c4) {
                float4 xv = xr[c4], wv = wr[c4];
                acc += xv.x * wv.x + xv.y * wv.y + xv.z * wv.z + xv.w * wv.w;
            }
        }
        mx = fmaxf(mx, acc);
    }
    red[sub][o] = mx;
    __syncthreads();
    if (tid < 32) {
        float m = red[0][tid];
#pragma unroll
        for (int s = 1; s < 8; ++s) m = fmaxf(m, red[s][tid]);
        pooled[b * Oo + tid] = m;
    }
}

// ---------- h0 = relu(pooled @ enc_w.T + enc_b) ----------
__global__ __launch_bounds__(256) void k_enc(const float* __restrict__ pooled,
                                             const float* __restrict__ ew,
                                             const float* __restrict__ eb,
                                             float* __restrict__ h) {
    __shared__ float ps[Oo];
    int b = blockIdx.x, tid = threadIdx.x;
    if (tid < Oo) ps[tid] = pooled[b * Oo + tid];
    __syncthreads();
    for (int j = tid; j < Hd; j += 256) {
        float acc = eb[j];
#pragma unroll
        for (int c = 0; c < Oo; ++c) acc += ps[c] * ew[j * Oo + c];
        h[(size_t)b * Hd + j] = fmaxf(acc, 0.f);
    }
}

// ---------- C[M=512, N] = A[512,1024] @ W[N,1024]^T + bias ----------
// thread = m (512 threads), block covers NT columns, W tile staged in LDS (broadcast reads)
template <int NT>
__global__ __launch_bounds__(512) void k_gemm(const float* __restrict__ A,
                                              const float* __restrict__ W,
                                              const float* __restrict__ bias,
                                              float* __restrict__ C, int N) {
    __shared__ __align__(16) float Wch[NT][64];
    int n0 = blockIdx.x * NT;
    int m = threadIdx.x;
    float acc[NT];
#pragma unroll
    for (int i = 0; i < NT; ++i) acc[i] = 0.f;
    const float4* A4 = (const float4*)(A + (size_t)m * Hd);
    for (int kc = 0; kc < Hd; kc += 64) {
        __syncthreads();
        for (int i = threadIdx.x; i < NT * 16; i += 512) {
            int r = i >> 4, c4 = i & 15;
            ((float4*)Wch[r])[c4] = ((const float4*)(W + (size_t)(n0 + r) * Hd + kc))[c4];
        }
        __syncthreads();
#pragma unroll
        for (int kk = 0; kk < 64; kk += 4) {
            float4 a0 = A4[(kc + kk) >> 2];
#pragma unroll
            for (int n = 0; n < NT; ++n) {
                float4 w = *(const float4*)&Wch[n][kk];
                acc[n] += a0.x * w.x + a0.y * w.y + a0.z * w.z + a0.w * w.w;
            }
        }
    }
#pragma unroll
    for (int n = 0; n < NT; ++n)
        C[(size_t)m * N + n0 + n] = acc[n] + bias[n0 + n];
}

// ---------- GRU gate math: h_new from gi (gathered by token) and gh ----------
__global__ __launch_bounds__(256) void k_gates(const float* __restrict__ gi_all,
                                               const int* __restrict__ tok,
                                               const float* __restrict__ gh,
                                               const float* __restrict__ h,
                                               float* __restrict__ hn,
                                               float* __restrict__ out_h) {
    int idx = blockIdx.x * 256 + threadIdx.x;   // < B*H
    int b = idx >> 10, j = idx & (Hd - 1);
    const float* gi = gi_all + (size_t)tok[b] * TH3;
    const float* ghb = gh + (size_t)b * TH3;
    float i_r = gi[j], i_z = gi[Hd + j], i_n = gi[2 * Hd + j];
    float h_r = ghb[j], h_z = ghb[Hd + j], h_n = ghb[2 * Hd + j];
    float r = 1.f / (1.f + expf(-(i_r + h_r)));
    float z = 1.f / (1.f + expf(-(i_z + h_z)));
    float nn = tanhf(i_n + r * h_n);
    float hv = (1.f - z) * nn + z * h[idx];
    hn[idx] = hv;
    out_h[idx] = hv;
}

// ---------- argmax per row (first-max ties), optional log_softmax on last step ----------
__global__ __launch_bounds__(256) void k_argmax(const float* __restrict__ logits,
                                                int* __restrict__ tok,
                                                float* __restrict__ out_idx,
                                                float* __restrict__ out_lsm,
                                                int do_lsm) {
    __shared__ float svals[256];
    __shared__ int sidx[256];
    __shared__ float ssum[256];
    int b = blockIdx.x, tid = threadIdx.x;
    const float* row = logits + (size_t)b * Vd;
    float bv = -3.4e38f;
    int bi = 0;
    for (int v = tid; v < Vd; v += 256) {
        float x = row[v];
        if (x > bv) { bv = x; bi = v; }
    }
    svals[tid] = bv; sidx[tid] = bi;
    __syncthreads();
    for (int s = 128; s > 0; s >>= 1) {
        if (tid < s) {
            float o = svals[tid + s]; int oi = sidx[tid + s];
            if (o > svals[tid] || (o == svals[tid] && oi < sidx[tid])) {
                svals[tid] = o; sidx[tid] = oi;
            }
        }
        __syncthreads();
    }
    if (tid == 0) {
        tok[b] = sidx[0];
        out_idx[b] = (float)sidx[0];
    }
    if (do_lsm) {
        float mx = svals[0];
        float ls = 0.f;
        for (int v = tid; v < Vd; v += 256) ls += expf(row[v] - mx);
        ssum[tid] = ls;
        __syncthreads();
        for (int s = 128; s > 0; s >>= 1) {
            if (tid < s) ssum[tid] += ssum[tid + s];
            __syncthreads();
        }
        float lse = logf(ssum[0]) + mx;
        for (int v = tid; v < Vd; v += 256)
            out_lsm[(size_t)b * Vd + v] = row[v] - lse;
    }
}

// ---------- init tokens to SOS and write decoded_indices row 0 ----------
__global__ void k_init(int* __restrict__ tok, float* __restrict__ out_idx0) {
    int i = blockIdx.x * 64 + threadIdx.x;
    if (i < Bsz) {
        tok[i] = 0;
        out_idx0[i] = 0.f;
    }
}

extern "C" void kernel_launch(void* const* d_in, const int* in_sizes, int n_in,
                              void* d_out, int out_size, void* d_ws, size_t ws_size,
                              hipStream_t stream) {
    const float* sm    = (const float*)d_in[0];
    const float* emb   = (const float*)d_in[1];
    const float* w_ih  = (const float*)d_in[2];
    const float* w_hh  = (const float*)d_in[3];
    const float* b_ih  = (const float*)d_in[4];
    const float* b_hh  = (const float*)d_in[5];
    const float* w_out = (const float*)d_in[6];
    const float* b_out = (const float*)d_in[7];
    const float* cw    = (const float*)d_in[8];
    const float* cb    = (const float*)d_in[9];
    const float* ew    = (const float*)d_in[10];
    const float* eb    = (const float*)d_in[11];

    float* out0 = (float*)d_out;                   // decoder_output  [512,512]
    float* out1 = out0 + (size_t)Bsz * Vd;         // decoder_hidden  [30,512,1024]
    float* out2 = out1 + (size_t)NSTEP * Bsz * Hd; // decoded_indices [31,512]

    char* wsp = (char*)d_ws;
    float* f_pool = (float*)wsp; wsp += sizeof(float) * Bsz * Oo;
    float* f_gi   = (float*)wsp; wsp += sizeof(float) * Vd * TH3;
    float* f_gh   = (float*)wsp; wsp += sizeof(float) * Bsz * TH3;
    float* f_hA   = (float*)wsp; wsp += sizeof(float) * Bsz * Hd;
    float* f_hB   = (float*)wsp; wsp += sizeof(float) * Bsz * Hd;
    float* f_log  = (float*)wsp; wsp += sizeof(float) * Bsz * Vd;
    float* cwT    = (float*)wsp; wsp += sizeof(float) * Oo * Cc * Kk;
    int*   tok    = (int*)wsp;   wsp += sizeof(int) * Bsz;

    // encoder + one-time precompute
    k_twt<<<(Oo * Cc * Kk + 255) / 256, 256, 0, stream>>>(cw, cwT);
    k_conv<<<Bsz, 256, 0, stream>>>(sm, cwT, cb, f_pool);
    k_enc<<<Bsz, 256, 0, stream>>>(f_pool, ew, eb, f_hA);
    // GI_all[v, 3072] = embedding[v] @ w_ih^T + b_ih  (token -> gi gather table)
    k_gemm<16><<<TH3 / 16, 512, 0, stream>>>(emb, w_ih, b_ih, f_gi, TH3);
    k_init<<<8, 64, 0, stream>>>(tok, out2);

    float* hcur = f_hA;
    float* hnew = f_hB;
    for (int t = 0; t < NSTEP; ++t) {
        k_gemm<16><<<TH3 / 16, 512, 0, stream>>>(hcur, w_hh, b_hh, f_gh, TH3);
        k_gates<<<(Bsz * Hd) / 256, 256, 0, stream>>>(f_gi, tok, f_gh, hcur, hnew,
                                                      out1 + (size_t)t * Bsz * Hd);
        k_gemm<4><<<Vd / 4, 512, 0, stream>>>(hnew, w_out, b_out, f_log, Vd);
        k_argmax<<<Bsz, 256, 0, stream>>>(f_log, tok, out2 + (size_t)(t + 1) * Bsz,
                                          out0, t == NSTEP - 1 ? 1 : 0);
        float* tmp = hcur; hcur = hnew; hnew = tmp;
    }
}

// Round 3
// 4481.895 us; speedup vs baseline: 1.6256x; 1.6256x over previous
//
#include <hip/hip_runtime.h>
#include <math.h>

#define Bsz 512
#define Hd 1024
#define Vd 512
#define Cc 128
#define Ll 120
#define Kk 10
#define Oo 32
#define Tt 111      // L - K + 1
#define NSTEP 30

static __device__ __forceinline__ float sigm(float x) { return 1.f / (1.f + expf(-x)); }

// ---------- conv_w [O,C,K] -> wT2 [K,C,O] so the 16-o slice is one s_load_dwordx16 ----------
__global__ void k_twt2(const float* __restrict__ cw, float* __restrict__ wT2) {
    int i = blockIdx.x * 256 + threadIdx.x;
    if (i < Oo * Cc * Kk) {
        int o = i / (Cc * Kk);
        int rem = i - o * (Cc * Kk);
        int c = rem / Kk;
        int k = rem - c * Kk;
        wT2[(k * Cc + c) * Oo + o] = cw[i];
    }
}

// ---------- fused conv1d + bias + relu + max-over-time + encoder FC -> h0 [B,H] ----------
// block = batch b; thread: t = tid&127 (time), half = tid>>7 (o-range 16)
__global__ __launch_bounds__(256) void k_convenc(const float* __restrict__ sm,
                                                 const float* __restrict__ wT2,
                                                 const float* __restrict__ cb,
                                                 const float* __restrict__ ew,
                                                 const float* __restrict__ eb,
                                                 float* __restrict__ h0) {
    __shared__ float xs[Ll * 129];   // padded rows: bank = t%32 -> 2-way alias (free)
    __shared__ float sred[4][16];
    __shared__ float ps[Oo];
    int b = blockIdx.x, tid = threadIdx.x;
    // stage sm[b] as [L][129]
    const float4* src = (const float4*)(sm + (size_t)b * Ll * Cc);
    for (int i = tid; i < Ll * (Cc / 4); i += 256) {
        int l = i >> 5, c4 = i & 31;
        float4 v = src[l * 32 + c4];
        float va[4] = {v.x, v.y, v.z, v.w};
        int base = l * 129 + c4 * 4;
#pragma unroll
        for (int q = 0; q < 4; ++q) xs[base + q] = va[q];
    }
    __syncthreads();

    int t = tid & 127;
    int o0 = __builtin_amdgcn_readfirstlane((tid >> 7) * 16);  // wave-uniform -> s_loads
    float acc[16];
#pragma unroll
    for (int oi = 0; oi < 16; ++oi) acc[oi] = -1e38f;
    if (t < Tt) {
#pragma unroll
        for (int oi = 0; oi < 16; ++oi) acc[oi] = 0.f;
        for (int k = 0; k < Kk; ++k) {
            int rowb = (t + k) * 129;
            const float* wk = wT2 + (size_t)k * Cc * Oo + o0;
#pragma unroll 2
            for (int c = 0; c < Cc; ++c) {
                float x = xs[rowb + c];
                const float* wp = wk + c * Oo;   // wave-uniform address
#pragma unroll
                for (int oi = 0; oi < 16; ++oi) acc[oi] += x * wp[oi];
            }
        }
    }
    // max over t within wave (lanes = 64 consecutive t, same o-range)
#pragma unroll
    for (int s = 1; s < 64; s <<= 1) {
#pragma unroll
        for (int oi = 0; oi < 16; ++oi)
            acc[oi] = fmaxf(acc[oi], __shfl_xor(acc[oi], s));
    }
    int wv = tid >> 6;
    if ((tid & 63) == 0) {
#pragma unroll
        for (int oi = 0; oi < 16; ++oi) sred[wv][oi] = acc[oi];
    }
    __syncthreads();
    if (tid < Oo) {
        int ho = tid >> 4, oi = tid & 15;
        float m = fmaxf(sred[ho * 2][oi], sred[ho * 2 + 1][oi]);
        ps[tid] = fmaxf(m + cb[tid], 0.f);
    }
    __syncthreads();
    // h0[b][j] = relu(ps . ew[j] + eb[j])
    for (int j = tid; j < Hd; j += 256) {
        float a = eb[j];
        const float4* e4 = (const float4*)(ew + (size_t)j * Oo);
#pragma unroll
        for (int c4 = 0; c4 < 8; ++c4) {
            float4 w = e4[c4];
            a += ps[c4 * 4 + 0] * w.x + ps[c4 * 4 + 1] * w.y +
                 ps[c4 * 4 + 2] * w.z + ps[c4 * 4 + 3] * w.w;
        }
        h0[(size_t)b * Hd + j] = fmaxf(a, 0.f);
    }
}

// ---------- fused [512 x (32j x 3gates) x 1024] GEMM (+ GRU gate epilogue) ----------
// GATES=0: C[v][g*1024+j] = emb@w_ih^T + b_ih (gi table)
// GATES=1: gh = h@w_hh^T; epilogue: gates with gi[tok], writes h_new + out1
// grid 256 blocks (1/CU, XCD-swizzled), 512 threads
template <int GATES>
__global__ __launch_bounds__(512) void k_step(const float* __restrict__ A,
                                              const float* __restrict__ W,
                                              const float* __restrict__ bias,   // b_ih or b_hh
                                              float* __restrict__ Cout,         // gi table or h_new
                                              const float* __restrict__ gi_all,
                                              const int* __restrict__ tok,
                                              const float* __restrict__ hOld,
                                              float* __restrict__ out1) {
    __shared__ float As[16][68];    // [kk][row], pad 68: a2 reads broadcast per ty
    __shared__ float Ws[16][100];   // [kk][s], s = g*32+jj; bank(kk*4 + tx*2) conflict-free
    int id = blockIdx.x;
    int xcd = id & 7, w = id >> 3;
    int jt = xcd * 4 + (w >> 3);    // 32 j-tiles: 4 per XCD -> W-panels stay in XCD L2
    int bt = w & 7;                 // 8 b-tiles
    int b0 = bt * 64, j0 = jt * 32;
    int tid = threadIdx.x;
    int ty = tid >> 4, tx = tid & 15;   // ty: 2 rows each; tx: 2 j each

    float acc[3][2][2];
#pragma unroll
    for (int g = 0; g < 3; ++g)
#pragma unroll
        for (int i = 0; i < 2; ++i)
#pragma unroll
            for (int j = 0; j < 2; ++j) acc[g][i][j] = 0.f;

    for (int kc = 0; kc < Hd; kc += 16) {
        __syncthreads();
        if (tid < 256) {
            int r = tid >> 2, c4 = tid & 3;
            float4 v = *(const float4*)&A[(size_t)(b0 + r) * Hd + kc + c4 * 4];
            float va[4] = {v.x, v.y, v.z, v.w};
#pragma unroll
            for (int q = 0; q < 4; ++q) As[c4 * 4 + q][r] = va[q];
        }
        if (tid < 384) {
            int s = tid >> 2, c4 = tid & 3;
            int wrow = (s >> 5) * Hd + j0 + (s & 31);
            float4 v = *(const float4*)&W[(size_t)wrow * Hd + kc + c4 * 4];
            float va[4] = {v.x, v.y, v.z, v.w};
#pragma unroll
            for (int q = 0; q < 4; ++q) Ws[c4 * 4 + q][s] = va[q];
        }
        __syncthreads();
#pragma unroll
        for (int kk = 0; kk < 16; ++kk) {
            float2 a2 = *(const float2*)&As[kk][ty * 2];
            float2 w0 = *(const float2*)&Ws[kk][tx * 2];
            float2 w1 = *(const float2*)&Ws[kk][32 + tx * 2];
            float2 w2 = *(const float2*)&Ws[kk][64 + tx * 2];
            float av[2] = {a2.x, a2.y};
            float wv[3][2] = {{w0.x, w0.y}, {w1.x, w1.y}, {w2.x, w2.y}};
#pragma unroll
            for (int i = 0; i < 2; ++i)
#pragma unroll
                for (int j = 0; j < 2; ++j) {
                    acc[0][i][j] += av[i] * wv[0][j];
                    acc[1][i][j] += av[i] * wv[1][j];
                    acc[2][i][j] += av[i] * wv[2][j];
                }
        }
    }

#pragma unroll
    for (int ib = 0; ib < 2; ++ib) {
        int b = b0 + ty * 2 + ib;
        if (GATES) {
            int tk = tok[b];
            const float* gi = gi_all + (size_t)tk * 3072;
#pragma unroll
            for (int jj = 0; jj < 2; ++jj) {
                int j = j0 + tx * 2 + jj;
                float hr = acc[0][ib][jj] + bias[j];
                float hz = acc[1][ib][jj] + bias[Hd + j];
                float hn = acc[2][ib][jj] + bias[2 * Hd + j];
                float r = sigm(gi[j] + hr);
                float z = sigm(gi[Hd + j] + hz);
                float n = tanhf(gi[2 * Hd + j] + r * hn);
                float hv = (1.f - z) * n + z * hOld[(size_t)b * Hd + j];
                Cout[(size_t)b * Hd + j] = hv;
                out1[(size_t)b * Hd + j] = hv;
            }
        } else {
#pragma unroll
            for (int jj = 0; jj < 2; ++jj) {
                int j = j0 + tx * 2 + jj;
#pragma unroll
                for (int g = 0; g < 3; ++g)
                    Cout[(size_t)b * 3072 + g * Hd + j] = acc[g][ib][jj] + bias[g * Hd + j];
            }
        }
    }
}

// ---------- logits GEMM: [512 x 512 x 1024], tile 32b x 64v, grid 128 ----------
__global__ __launch_bounds__(256) void k_logits(const float* __restrict__ A,
                                                const float* __restrict__ W,
                                                const float* __restrict__ bias,
                                                float* __restrict__ C) {
    __shared__ float As[16][34];
    __shared__ float Ws[16][68];
    int id = blockIdx.x;
    int vt = id & 7, bt = id >> 3;   // 8 v-tiles (1/XCD), 16 b-tiles
    int b0 = bt * 32, v0 = vt * 64;
    int tid = threadIdx.x;
    int ty = tid >> 4, tx = tid & 15;
    float acc[2][4];
#pragma unroll
    for (int i = 0; i < 2; ++i)
#pragma unroll
        for (int q = 0; q < 4; ++q) acc[i][q] = 0.f;

    for (int kc = 0; kc < Hd; kc += 16) {
        __syncthreads();
        if (tid < 128) {
            int r = tid >> 2, c4 = tid & 3;
            float4 v = *(const float4*)&A[(size_t)(b0 + r) * Hd + kc + c4 * 4];
            float va[4] = {v.x, v.y, v.z, v.w};
#pragma unroll
            for (int q = 0; q < 4; ++q) As[c4 * 4 + q][r] = va[q];
        }
        {
            int s = tid >> 2, c4 = tid & 3;
            float4 v = *(const float4*)&W[(size_t)(v0 + s) * Hd + kc + c4 * 4];
            float va[4] = {v.x, v.y, v.z, v.w};
#pragma unroll
            for (int q = 0; q < 4; ++q) Ws[c4 * 4 + q][s] = va[q];
        }
        __syncthreads();
#pragma unroll
        for (int kk = 0; kk < 16; ++kk) {
            float2 a2 = *(const float2*)&As[kk][ty * 2];
            float4 w4 = *(const float4*)&Ws[kk][tx * 4];
            float av[2] = {a2.x, a2.y};
            float wv[4] = {w4.x, w4.y, w4.z, w4.w};
#pragma unroll
            for (int i = 0; i < 2; ++i)
#pragma unroll
                for (int q = 0; q < 4; ++q) acc[i][q] += av[i] * wv[q];
        }
    }
#pragma unroll
    for (int i = 0; i < 2; ++i) {
        int b = b0 + ty * 2 + i;
#pragma unroll
        for (int q = 0; q < 4; ++q) {
            int v = v0 + tx * 4 + q;
            C[(size_t)b * Vd + v] = acc[i][q] + bias[v];
        }
    }
}

// ---------- argmax per row (first-max ties), optional log_softmax on last step ----------
__global__ __launch_bounds__(256) void k_argmax(const float* __restrict__ logits,
                                                int* __restrict__ tok,
                                                float* __restrict__ out_idx,
                                                float* __restrict__ out_lsm,
                                                int do_lsm) {
    __shared__ float svals[256];
    __shared__ int sidx[256];
    __shared__ float ssum[256];
    int b = blockIdx.x, tid = threadIdx.x;
    const float* row = logits + (size_t)b * Vd;
    float bv = -3.4e38f;
    int bi = 0;
    for (int v = tid; v < Vd; v += 256) {
        float x = row[v];
        if (x > bv) { bv = x; bi = v; }
    }
    svals[tid] = bv; sidx[tid] = bi;
    __syncthreads();
    for (int s = 128; s > 0; s >>= 1) {
        if (tid < s) {
            float o = svals[tid + s]; int oi = sidx[tid + s];
            if (o > svals[tid] || (o == svals[tid] && oi < sidx[tid])) {
                svals[tid] = o; sidx[tid] = oi;
            }
        }
        __syncthreads();
    }
    if (tid == 0) {
        tok[b] = sidx[0];
        out_idx[b] = (float)sidx[0];
    }
    if (do_lsm) {
        float mx = svals[0];
        float ls = 0.f;
        for (int v = tid; v < Vd; v += 256) ls += expf(row[v] - mx);
        ssum[tid] = ls;
        __syncthreads();
        for (int s = 128; s > 0; s >>= 1) {
            if (tid < s) ssum[tid] += ssum[tid + s];
            __syncthreads();
        }
        float lse = logf(ssum[0]) + mx;
        for (int v = tid; v < Vd; v += 256)
            out_lsm[(size_t)b * Vd + v] = row[v] - lse;
    }
}

__global__ void k_init(int* __restrict__ tok, float* __restrict__ out_idx0) {
    int i = blockIdx.x * 64 + threadIdx.x;
    if (i < Bsz) {
        tok[i] = 0;
        out_idx0[i] = 0.f;
    }
}

extern "C" void kernel_launch(void* const* d_in, const int* in_sizes, int n_in,
                              void* d_out, int out_size, void* d_ws, size_t ws_size,
                              hipStream_t stream) {
    const float* sm    = (const float*)d_in[0];
    const float* emb   = (const float*)d_in[1];
    const float* w_ih  = (const float*)d_in[2];
    const float* w_hh  = (const float*)d_in[3];
    const float* b_ih  = (const float*)d_in[4];
    const float* b_hh  = (const float*)d_in[5];
    const float* w_out = (const float*)d_in[6];
    const float* b_out = (const float*)d_in[7];
    const float* cw    = (const float*)d_in[8];
    const float* cb    = (const float*)d_in[9];
    const float* ew    = (const float*)d_in[10];
    const float* eb    = (const float*)d_in[11];

    float* out0 = (float*)d_out;                   // decoder_output  [512,512]
    float* out1 = out0 + (size_t)Bsz * Vd;         // decoder_hidden  [30,512,1024]
    float* out2 = out1 + (size_t)NSTEP * Bsz * Hd; // decoded_indices [31,512]

    char* wsp = (char*)d_ws;
    float* f_gi  = (float*)wsp; wsp += sizeof(float) * Vd * 3072;
    float* f_hA  = (float*)wsp; wsp += sizeof(float) * Bsz * Hd;
    float* f_hB  = (float*)wsp; wsp += sizeof(float) * Bsz * Hd;
    float* f_log = (float*)wsp; wsp += sizeof(float) * Bsz * Vd;
    float* wT2   = (float*)wsp; wsp += sizeof(float) * Kk * Cc * Oo;
    int*   tok   = (int*)wsp;   wsp += sizeof(int) * Bsz;

    k_twt2<<<(Oo * Cc * Kk + 255) / 256, 256, 0, stream>>>(cw, wT2);
    k_convenc<<<Bsz, 256, 0, stream>>>(sm, wT2, cb, ew, eb, f_hA);
    // gi table: emb @ w_ih^T + b_ih for all 512 tokens
    k_step<0><<<256, 512, 0, stream>>>(emb, w_ih, b_ih, f_gi,
                                       nullptr, nullptr, nullptr, nullptr);
    k_init<<<8, 64, 0, stream>>>(tok, out2);

    float* hcur = f_hA;
    float* hnew = f_hB;
    for (int t = 0; t < NSTEP; ++t) {
        k_step<1><<<256, 512, 0, stream>>>(hcur, w_hh, b_hh, hnew,
                                           f_gi, tok, hcur,
                                           out1 + (size_t)t * Bsz * Hd);
        k_logits<<<128, 256, 0, stream>>>(hnew, w_out, b_out, f_log);
        k_argmax<<<Bsz, 256, 0, stream>>>(f_log, tok, out2 + (size_t)(t + 1) * Bsz,
                                          out0, t == NSTEP - 1 ? 1 : 0);
        float* tmp = hcur; hcur = hnew; hnew = tmp;
    }
}

// Round 4
// 1625.132 us; speedup vs baseline: 4.4833x; 2.7579x over previous
//
#include <hip/hip_runtime.h>
#include <hip/hip_bf16.h>
#include <math.h>

#define Bsz 512
#define Hd 1024
#define Vd 512
#define Cc 128
#define Ll 120
#define Kk 10
#define Oo 32
#define Tt 111
#define NSTEP 30

typedef __attribute__((ext_vector_type(8))) short bf16x8;
typedef __attribute__((ext_vector_type(4))) float f32x4;
typedef unsigned short ushort;

static __device__ __forceinline__ float sigm(float x) { return 1.f / (1.f + expf(-x)); }
static __device__ __forceinline__ ushort f2bf(float x) {
    __hip_bfloat16 h = __float2bfloat16(x);
    return *(ushort*)&h;
}
static __device__ __forceinline__ float bf2f(ushort u) {
    __hip_bfloat16 h; *(ushort*)&h = u;
    return __bfloat162float(h);
}

// ---------- pack + split f32 row-major W[N][1024] into MFMA-frag layout ----------
// layout: [nf][c][lane][jj] : element = W[nf*16 + (lane&15)][c*32 + (lane>>4)*8 + jj]
__global__ void k_pack(const float* __restrict__ W, ushort* __restrict__ hi,
                       ushort* __restrict__ lo, int total) {
    int idx = blockIdx.x * 256 + threadIdx.x;
    if (idx >= total) return;
    int jj = idx & 7, l = (idx >> 3) & 63, c = (idx >> 9) & 31, nf = idx >> 14;
    int n = nf * 16 + (l & 15);
    int k = c * 32 + ((l >> 4) << 3) + jj;
    float v = W[(size_t)n * 1024 + k];
    ushort h = f2bf(v);
    hi[idx] = h;
    lo[idx] = f2bf(v - bf2f(h));
}

// ---------- conv_w [O,C,K] -> wT2 [K,C,O] ----------
__global__ void k_twt2(const float* __restrict__ cw, float* __restrict__ wT2) {
    int i = blockIdx.x * 256 + threadIdx.x;
    if (i < Oo * Cc * Kk) {
        int o = i / (Cc * Kk);
        int rem = i - o * (Cc * Kk);
        int c = rem / Kk;
        int k = rem - c * Kk;
        wT2[(k * Cc + c) * Oo + o] = cw[i];
    }
}

// ---------- fused conv+pool+encoder -> h0 (f32 + packed split bf16) ----------
__global__ __launch_bounds__(512) void k_convenc(const float* __restrict__ sm,
                                                 const float* __restrict__ wT2,
                                                 const float* __restrict__ cb,
                                                 const float* __restrict__ ew,
                                                 const float* __restrict__ eb,
                                                 float* __restrict__ h0,
                                                 ushort* __restrict__ ApHi,
                                                 ushort* __restrict__ ApLo) {
    __shared__ float xs[Ll * 129];
    __shared__ float sred[8][8];
    __shared__ float ps[Oo];
    int b = blockIdx.x, tid = threadIdx.x;
    const float4* src = (const float4*)(sm + (size_t)b * Ll * Cc);
    for (int i = tid; i < Ll * (Cc / 4); i += 512) {
        int l = i >> 5, c4 = i & 31;
        float4 v = src[l * 32 + c4];
        float va[4] = {v.x, v.y, v.z, v.w};
        int base = l * 129 + c4 * 4;
#pragma unroll
        for (int q = 0; q < 4; ++q) xs[base + q] = va[q];
    }
    __syncthreads();

    int t = tid & 127;
    int o0 = __builtin_amdgcn_readfirstlane((tid >> 7) * 8);
    float acc[8];
#pragma unroll
    for (int oi = 0; oi < 8; ++oi) acc[oi] = -1e38f;
    if (t < Tt) {
#pragma unroll
        for (int oi = 0; oi < 8; ++oi) acc[oi] = 0.f;
        for (int k = 0; k < Kk; ++k) {
            int rowb = (t + k) * 129;
            const float* wk = wT2 + (size_t)k * Cc * Oo + o0;
#pragma unroll 2
            for (int c = 0; c < Cc; ++c) {
                float x = xs[rowb + c];
                const float* wp = wk + c * Oo;   // wave-uniform -> s_load
#pragma unroll
                for (int oi = 0; oi < 8; ++oi) acc[oi] += x * wp[oi];
            }
        }
    }
#pragma unroll
    for (int s = 1; s < 64; s <<= 1) {
#pragma unroll
        for (int oi = 0; oi < 8; ++oi)
            acc[oi] = fmaxf(acc[oi], __shfl_xor(acc[oi], s));
    }
    int wid = tid >> 6;
    if ((tid & 63) == 0) {
#pragma unroll
        for (int oi = 0; oi < 8; ++oi) sred[wid][oi] = acc[oi];
    }
    __syncthreads();
    if (tid < Oo) {
        int oq = tid >> 3;
        float m = fmaxf(sred[oq * 2][tid & 7], sred[oq * 2 + 1][tid & 7]);
        ps[tid] = fmaxf(m + cb[tid], 0.f);
    }
    __syncthreads();
    for (int j = tid; j < Hd; j += 512) {
        float a = eb[j];
        const float4* e4 = (const float4*)(ew + (size_t)j * Oo);
#pragma unroll
        for (int c4 = 0; c4 < 8; ++c4) {
            float4 w = e4[c4];
            a += ps[c4 * 4 + 0] * w.x + ps[c4 * 4 + 1] * w.y +
                 ps[c4 * 4 + 2] * w.z + ps[c4 * 4 + 3] * w.w;
        }
        a = fmaxf(a, 0.f);
        h0[(size_t)b * Hd + j] = a;
        ushort hb = f2bf(a);
        ushort lb = f2bf(a - bf2f(hb));
        int c = j >> 5, sub = (j >> 3) & 3, jj = j & 7, mf = b >> 4, lr = b & 15;
        int flat = ((mf * 32 + c) * 64 + lr + (sub << 4)) * 8 + jj;
        ApHi[flat] = hb;
        ApLo[flat] = lb;
    }
}

// ---------- MFMA split-bf16 GEMM + fused epilogues ----------
// C[b][g*NP+j] = A[b][:] . W[g*NP+j][:]  (K=1024), 3-term split product
// EPI 0: store acc+bias (gi table). EPI 1: GRU gates -> h_new (+pack). EPI 2: logits.
template <int G, int NP, int EPI>
__global__ __launch_bounds__(256) void k_gemm(const ushort* __restrict__ Ah,
                                              const ushort* __restrict__ Al,
                                              const ushort* __restrict__ Bh,
                                              const ushort* __restrict__ Bl,
                                              const float* __restrict__ bias,
                                              float* __restrict__ outF,
                                              const float* __restrict__ gi_all,
                                              const int* __restrict__ tok,
                                              const float* __restrict__ hOld,
                                              float* __restrict__ hNewF,
                                              ushort* __restrict__ ApHi,
                                              ushort* __restrict__ ApLo) {
    constexpr int NT = NP / 32;       // j-tiles of 32
    constexpr int PX = NT / 8;        // j-tiles per XCD
    int id = blockIdx.x;
    int xcd = id & 7, r = id >> 3;
    int jt = xcd * PX + (r % PX);
    int mt = r / PX;
    int tid = threadIdx.x;
    int wid = tid >> 6, l = tid & 63;
    int wm = wid >> 1, wj = wid & 1;

    int mfb = mt * 4 + wm * 2;
    int ab[2], bb[G];
#pragma unroll
    for (int mi = 0; mi < 2; ++mi) ab[mi] = ((mfb + mi) * 32) * 512 + l * 8;
#pragma unroll
    for (int g = 0; g < G; ++g)
        bb[g] = ((g * (NP / 16) + jt * 2 + wj) * 32) * 512 + l * 8;

    f32x4 acc[2][G];
#pragma unroll
    for (int mi = 0; mi < 2; ++mi)
#pragma unroll
        for (int g = 0; g < G; ++g) acc[mi][g] = (f32x4)0.f;

    bf16x8 ah0[2], al0[2], bh0[G], bl0[G];
    bf16x8 ah1[2], al1[2], bh1[G], bl1[G];

#define LDF(AH, AL, BH, BL, c)                                             \
    {                                                                      \
        _Pragma("unroll") for (int mi = 0; mi < 2; ++mi) {                 \
            AH[mi] = *(const bf16x8*)(Ah + ab[mi] + (c) * 512);            \
            AL[mi] = *(const bf16x8*)(Al + ab[mi] + (c) * 512);            \
        }                                                                  \
        _Pragma("unroll") for (int g = 0; g < G; ++g) {                    \
            BH[g] = *(const bf16x8*)(Bh + bb[g] + (c) * 512);              \
            BL[g] = *(const bf16x8*)(Bl + bb[g] + (c) * 512);              \
        }                                                                  \
    }
#define STP(AH, AL, BH, BL)                                                \
    {                                                                      \
        _Pragma("unroll") for (int g = 0; g < G; ++g)                      \
            _Pragma("unroll") for (int mi = 0; mi < 2; ++mi)               \
                acc[mi][g] = __builtin_amdgcn_mfma_f32_16x16x32_bf16(      \
                    AH[mi], BH[g], acc[mi][g], 0, 0, 0);                   \
        _Pragma("unroll") for (int g = 0; g < G; ++g)                      \
            _Pragma("unroll") for (int mi = 0; mi < 2; ++mi)               \
                acc[mi][g] = __builtin_amdgcn_mfma_f32_16x16x32_bf16(      \
                    AH[mi], BL[g], acc[mi][g], 0, 0, 0);                   \
        _Pragma("unroll") for (int g = 0; g < G; ++g)                      \
            _Pragma("unroll") for (int mi = 0; mi < 2; ++mi)               \
                acc[mi][g] = __builtin_amdgcn_mfma_f32_16x16x32_bf16(      \
                    AL[mi], BH[g], acc[mi][g], 0, 0, 0);                   \
    }

    LDF(ah0, al0, bh0, bl0, 0)
#pragma unroll
    for (int c = 0; c < 32; c += 2) {
        LDF(ah1, al1, bh1, bl1, c + 1)
        STP(ah0, al0, bh0, bl0)
        if (c + 2 < 32) LDF(ah0, al0, bh0, bl0, c + 2)
        STP(ah1, al1, bh1, bl1)
    }
#undef LDF
#undef STP

    int j = jt * 32 + wj * 16 + (l & 15);
    int rbase = mt * 64 + wm * 32 + ((l >> 4) << 2);

    if (EPI == 0) {
#pragma unroll
        for (int mi = 0; mi < 2; ++mi)
#pragma unroll
            for (int g = 0; g < G; ++g)
#pragma unroll
                for (int q = 0; q < 4; ++q) {
                    int b = rbase + mi * 16 + q;
                    outF[(size_t)b * (G * NP) + g * NP + j] =
                        acc[mi][g][q] + bias[g * NP + j];
                }
    } else if (EPI == 2) {
        float bj = bias[j];
#pragma unroll
        for (int mi = 0; mi < 2; ++mi)
#pragma unroll
            for (int q = 0; q < 4; ++q) {
                int b = rbase + mi * 16 + q;
                outF[(size_t)b * NP + j] = acc[mi][0][q] + bj;
            }
    } else {
        float bh_r = bias[j], bh_z = bias[1024 + j], bh_n = bias[2048 + j];
        int c = j >> 5, sub = (j >> 3) & 3, jj = j & 7;
#pragma unroll
        for (int mi = 0; mi < 2; ++mi)
#pragma unroll
            for (int q = 0; q < 4; ++q) {
                int b = rbase + mi * 16 + q;
                const float* gi = gi_all + (size_t)tok[b] * 3072;
                float rr = sigm(gi[j] + acc[mi][0][q] + bh_r);
                float zz = sigm(gi[1024 + j] + acc[mi][1][q] + bh_z);
                float nn = tanhf(gi[2048 + j] + rr * (acc[mi][2][q] + bh_n));
                float hv = (1.f - zz) * nn + zz * hOld[(size_t)b * 1024 + j];
                hNewF[(size_t)b * 1024 + j] = hv;
                outF[(size_t)b * 1024 + j] = hv;
                ushort hb = f2bf(hv);
                ushort lb = f2bf(hv - bf2f(hb));
                int mf = b >> 4, lr = b & 15;
                int flat = ((mf * 32 + c) * 64 + lr + (sub << 4)) * 8 + jj;
                ApHi[flat] = hb;
                ApLo[flat] = lb;
            }
    }
}

// ---------- wave-per-row argmax (+ log_softmax on last step) ----------
__global__ __launch_bounds__(64) void k_argmax(const float* __restrict__ logits,
                                               int* __restrict__ tok,
                                               float* __restrict__ out_idx,
                                               float* __restrict__ out_lsm,
                                               int do_lsm) {
    int b = blockIdx.x, l = threadIdx.x;
    const float* row = logits + (size_t)b * Vd;
    float bv = -3.4e38f;
    int bi = 0;
#pragma unroll
    for (int s = 0; s < 8; ++s) {
        int v = s * 64 + l;
        float x = row[v];
        if (x > bv) { bv = x; bi = v; }
    }
#pragma unroll
    for (int off = 1; off < 64; off <<= 1) {
        float ov = __shfl_xor(bv, off);
        int oi = __shfl_xor(bi, off);
        if (ov > bv || (ov == bv && oi < bi)) { bv = ov; bi = oi; }
    }
    if (l == 0) {
        tok[b] = bi;
        out_idx[b] = (float)bi;
    }
    if (do_lsm) {
        float sum = 0.f;
#pragma unroll
        for (int s = 0; s < 8; ++s) sum += expf(row[s * 64 + l] - bv);
#pragma unroll
        for (int off = 1; off < 64; off <<= 1) sum += __shfl_xor(sum, off);
        float lse = logf(sum) + bv;
#pragma unroll
        for (int s = 0; s < 8; ++s) {
            int v = s * 64 + l;
            out_lsm[(size_t)b * Vd + v] = row[v] - lse;
        }
    }
}

__global__ void k_init(int* __restrict__ tok, float* __restrict__ out_idx0) {
    int i = blockIdx.x * 64 + threadIdx.x;
    if (i < Bsz) {
        tok[i] = 0;
        out_idx0[i] = 0.f;
    }
}

extern "C" void kernel_launch(void* const* d_in, const int* in_sizes, int n_in,
                              void* d_out, int out_size, void* d_ws, size_t ws_size,
                              hipStream_t stream) {
    const float* sm    = (const float*)d_in[0];
    const float* emb   = (const float*)d_in[1];
    const float* w_ih  = (const float*)d_in[2];
    const float* w_hh  = (const float*)d_in[3];
    const float* b_ih  = (const float*)d_in[4];
    const float* b_hh  = (const float*)d_in[5];
    const float* w_out = (const float*)d_in[6];
    const float* b_out = (const float*)d_in[7];
    const float* cw    = (const float*)d_in[8];
    const float* cb    = (const float*)d_in[9];
    const float* ew    = (const float*)d_in[10];
    const float* eb    = (const float*)d_in[11];

    float* out0 = (float*)d_out;
    float* out1 = out0 + (size_t)Bsz * Vd;
    float* out2 = out1 + (size_t)NSTEP * Bsz * Hd;

    char* wsp = (char*)d_ws;
    float*  f_gi  = (float*)wsp;  wsp += sizeof(float) * Bsz * 3072;
    float*  f_h0  = (float*)wsp;  wsp += sizeof(float) * Bsz * Hd;
    float*  f_h1  = (float*)wsp;  wsp += sizeof(float) * Bsz * Hd;
    float*  f_log = (float*)wsp;  wsp += sizeof(float) * Bsz * Vd;
    ushort* ApHi0 = (ushort*)wsp; wsp += sizeof(ushort) * Bsz * Hd;
    ushort* ApLo0 = (ushort*)wsp; wsp += sizeof(ushort) * Bsz * Hd;
    ushort* ApHi1 = (ushort*)wsp; wsp += sizeof(ushort) * Bsz * Hd;
    ushort* ApLo1 = (ushort*)wsp; wsp += sizeof(ushort) * Bsz * Hd;
    ushort* embH  = (ushort*)wsp; wsp += sizeof(ushort) * Vd * Hd;
    ushort* embL  = (ushort*)wsp; wsp += sizeof(ushort) * Vd * Hd;
    ushort* wihH  = (ushort*)wsp; wsp += sizeof(ushort) * 3072 * Hd;
    ushort* wihL  = (ushort*)wsp; wsp += sizeof(ushort) * 3072 * Hd;
    ushort* whhH  = (ushort*)wsp; wsp += sizeof(ushort) * 3072 * Hd;
    ushort* whhL  = (ushort*)wsp; wsp += sizeof(ushort) * 3072 * Hd;
    ushort* woutH = (ushort*)wsp; wsp += sizeof(ushort) * Vd * Hd;
    ushort* woutL = (ushort*)wsp; wsp += sizeof(ushort) * Vd * Hd;
    float*  wT2   = (float*)wsp;  wsp += sizeof(float) * Kk * Cc * Oo;
    int*    tok   = (int*)wsp;    wsp += sizeof(int) * Bsz;

    // one-time setup
    k_twt2<<<(Oo * Cc * Kk + 255) / 256, 256, 0, stream>>>(cw, wT2);
    k_pack<<<(3072 * 1024) / 256, 256, 0, stream>>>(w_ih, wihH, wihL, 3072 * 1024);
    k_pack<<<(3072 * 1024) / 256, 256, 0, stream>>>(w_hh, whhH, whhL, 3072 * 1024);
    k_pack<<<(512 * 1024) / 256, 256, 0, stream>>>(w_out, woutH, woutL, 512 * 1024);
    k_pack<<<(512 * 1024) / 256, 256, 0, stream>>>(emb, embH, embL, 512 * 1024);
    k_convenc<<<Bsz, 512, 0, stream>>>(sm, wT2, cb, ew, eb, f_h0, ApHi0, ApLo0);
    // gi table: emb @ w_ih^T + b_ih for all 512 tokens
    k_gemm<3, 1024, 0><<<256, 256, 0, stream>>>(embH, embL, wihH, wihL, b_ih, f_gi,
                                                nullptr, nullptr, nullptr, nullptr,
                                                nullptr, nullptr);
    k_init<<<8, 64, 0, stream>>>(tok, out2);

    float*  fh[2] = {f_h0, f_h1};
    ushort* aH[2] = {ApHi0, ApHi1};
    ushort* aL[2] = {ApLo0, ApLo1};
    for (int t = 0; t < NSTEP; ++t) {
        int cur = t & 1, nxt = cur ^ 1;
        k_gemm<3, 1024, 1><<<256, 256, 0, stream>>>(
            aH[cur], aL[cur], whhH, whhL, b_hh, out1 + (size_t)t * Bsz * Hd,
            f_gi, tok, fh[cur], fh[nxt], aH[nxt], aL[nxt]);
        k_gemm<1, 512, 2><<<128, 256, 0, stream>>>(
            aH[nxt], aL[nxt], woutH, woutL, b_out, f_log,
            nullptr, nullptr, nullptr, nullptr, nullptr, nullptr);
        k_argmax<<<Bsz, 64, 0, stream>>>(f_log, tok, out2 + (size_t)(t + 1) * Bsz,
                                         out0, t == NSTEP - 1 ? 1 : 0);
    }
}

// Round 6
// 828.300 us; speedup vs baseline: 8.7963x; 1.9620x over previous
//
#include <hip/hip_runtime.h>
#include <hip/hip_bf16.h>
#include <math.h>

#define Bsz 512
#define Hd 1024
#define Vd 512
#define Cc 128
#define Ll 120
#define Kk 10
#define Oo 32
#define NSTEP 30

typedef __attribute__((ext_vector_type(8))) short bf16x8;
typedef __attribute__((ext_vector_type(4))) float f32x4;
typedef unsigned short ushort;

static __device__ __forceinline__ float sigm(float x) { return 1.f / (1.f + expf(-x)); }
static __device__ __forceinline__ ushort f2bf(float x) {
    __hip_bfloat16 h = __float2bfloat16(x);
    return *(ushort*)&h;
}
static __device__ __forceinline__ float bf2f(ushort u) {
    __hip_bfloat16 h; *(ushort*)&h = u;
    return __bfloat162float(h);
}

// ---------- split f32 -> hi/lo bf16 elementwise ----------
__global__ void k_split(const float* __restrict__ in, ushort* __restrict__ hi,
                        ushort* __restrict__ lo, int n) {
    int i = blockIdx.x * 256 + threadIdx.x;
    if (i < n) {
        float v = in[i];
        ushort h = f2bf(v);
        hi[i] = h;
        lo[i] = f2bf(v - bf2f(h));
    }
}

// ---------- pack + split W[N][1024] into MFMA frag layout ----------
// flat = ((nf*32 + c)*64 + l)*8 + jj ; element = W[nf*16 + (l&15)][c*32 + (l>>4)*8 + jj]
__global__ void k_pack(const float* __restrict__ W, ushort* __restrict__ hi,
                       ushort* __restrict__ lo, int total) {
    int idx = blockIdx.x * 256 + threadIdx.x;
    if (idx >= total) return;
    int jj = idx & 7, l = (idx >> 3) & 63, c = (idx >> 9) & 31, nf = idx >> 14;
    int n = nf * 16 + (l & 15);
    int k = c * 32 + ((l >> 4) << 3) + jj;
    float v = W[(size_t)n * 1024 + k];
    ushort h = f2bf(v);
    hi[idx] = h;
    lo[idx] = f2bf(v - bf2f(h));
}

// ---------- pack conv_w [O,C,K] into B-frag layout over K'=(kconv,c)=1280 ----------
__global__ void k_packconv(const float* __restrict__ cw, ushort* __restrict__ hi,
                           ushort* __restrict__ lo) {
    int idx = blockIdx.x * 256 + threadIdx.x;
    if (idx >= 2 * 40 * 64 * 8) return;
    int jj = idx & 7, l = (idx >> 3) & 63, ch = (idx >> 9) % 40, nf = idx / (40 * 512);
    int o = nf * 16 + (l & 15);
    int k = ch * 32 + ((l >> 4) << 3) + jj;
    int kc = k >> 7, c = k & 127;
    float v = cw[(o * Cc + c) * Kk + kc];
    ushort h = f2bf(v);
    hi[idx] = h;
    lo[idx] = f2bf(v - bf2f(h));
}

// ---------- conv as MFMA GEMM (M=t, N=32 o, K=1280) + masked max + encoder FC ----------
__global__ __launch_bounds__(256) void k_convmfma(const ushort* __restrict__ xH,
                                                  const ushort* __restrict__ xL,
                                                  const ushort* __restrict__ wH,
                                                  const ushort* __restrict__ wL,
                                                  const float* __restrict__ cb,
                                                  const float* __restrict__ ew,
                                                  const float* __restrict__ eb,
                                                  float* __restrict__ h0,
                                                  ushort* __restrict__ ApHi,
                                                  ushort* __restrict__ ApLo) {
    __shared__ float sred[4][2][16];
    __shared__ float ps[Oo];
    int b = blockIdx.x, tid = threadIdx.x, wid = tid >> 6, l = tid & 63;
    f32x4 acc[2][2];
#pragma unroll
    for (int i = 0; i < 2; ++i)
#pragma unroll
        for (int j = 0; j < 2; ++j) acc[i][j] = (f32x4)0.f;

    bf16x8 aH0[2], aL0[2], bH0[2], bL0[2];
    bf16x8 aH1[2], aL1[2], bH1[2], bL1[2];

#define CLD(AH, AL, BH, BL, ch)                                                        \
    {                                                                                  \
        _Pragma("unroll") for (int tf2 = 0; tf2 < 2; ++tf2) {                          \
            int aoff = ((b * 120 + (wid * 2 + tf2) * 16 + (l & 15) + ((ch) >> 2)) * 128 \
                        + ((ch) & 3) * 32 + ((l >> 4) << 3));                          \
            AH[tf2] = *(const bf16x8*)(xH + aoff);                                     \
            AL[tf2] = *(const bf16x8*)(xL + aoff);                                     \
        }                                                                              \
        _Pragma("unroll") for (int nf = 0; nf < 2; ++nf) {                             \
            int boff = ((nf * 40 + (ch)) * 64 + l) * 8;                                \
            BH[nf] = *(const bf16x8*)(wH + boff);                                      \
            BL[nf] = *(const bf16x8*)(wL + boff);                                      \
        }                                                                              \
    }
#define CST(AH, AL, BH, BL)                                                            \
    {                                                                                  \
        _Pragma("unroll") for (int tf2 = 0; tf2 < 2; ++tf2)                            \
            _Pragma("unroll") for (int nf = 0; nf < 2; ++nf) {                         \
                acc[tf2][nf] = __builtin_amdgcn_mfma_f32_16x16x32_bf16(                \
                    AH[tf2], BH[nf], acc[tf2][nf], 0, 0, 0);                           \
                acc[tf2][nf] = __builtin_amdgcn_mfma_f32_16x16x32_bf16(                \
                    AH[tf2], BL[nf], acc[tf2][nf], 0, 0, 0);                           \
                acc[tf2][nf] = __builtin_amdgcn_mfma_f32_16x16x32_bf16(                \
                    AL[tf2], BH[nf], acc[tf2][nf], 0, 0, 0);                           \
            }                                                                          \
    }

    CLD(aH0, aL0, bH0, bL0, 0)
#pragma unroll
    for (int ch = 0; ch < 40; ch += 2) {
        CLD(aH1, aL1, bH1, bL1, ch + 1)
        CST(aH0, aL0, bH0, bL0)
        if (ch + 2 < 40) CLD(aH0, aL0, bH0, bL0, ch + 2)
        CST(aH1, aL1, bH1, bL1)
    }
#undef CLD
#undef CST

    float mx[2] = {-1e38f, -1e38f};
#pragma unroll
    for (int tf2 = 0; tf2 < 2; ++tf2) {
        int tb = (wid * 2 + tf2) * 16 + ((l >> 4) << 2);
#pragma unroll
        for (int q = 0; q < 4; ++q) {
            if (tb + q <= 110) {
                mx[0] = fmaxf(mx[0], acc[tf2][0][q]);
                mx[1] = fmaxf(mx[1], acc[tf2][1][q]);
            }
        }
    }
#pragma unroll
    for (int s = 16; s < 64; s <<= 1) {
        mx[0] = fmaxf(mx[0], __shfl_xor(mx[0], s));
        mx[1] = fmaxf(mx[1], __shfl_xor(mx[1], s));
    }
    if (l < 16) {
        sred[wid][0][l] = mx[0];
        sred[wid][1][l] = mx[1];
    }
    __syncthreads();
    if (tid < Oo) {
        float m = sred[0][tid >> 4][tid & 15];
#pragma unroll
        for (int w = 1; w < 4; ++w) m = fmaxf(m, sred[w][tid >> 4][tid & 15]);
        ps[tid] = fmaxf(m + cb[tid], 0.f);
    }
    __syncthreads();
    for (int j = tid; j < Hd; j += 256) {
        float a = eb[j];
        const float4* e4 = (const float4*)(ew + (size_t)j * Oo);
#pragma unroll
        for (int c4 = 0; c4 < 8; ++c4) {
            float4 w = e4[c4];
            a += ps[c4 * 4 + 0] * w.x + ps[c4 * 4 + 1] * w.y +
                 ps[c4 * 4 + 2] * w.z + ps[c4 * 4 + 3] * w.w;
        }
        a = fmaxf(a, 0.f);
        h0[(size_t)b * Hd + j] = a;
        ushort hb = f2bf(a);
        ushort lb = f2bf(a - bf2f(hb));
        int c = j >> 5, sub = (j >> 3) & 3, jj = j & 7, mf = b >> 4;
        int lane_r = (b & 15) + (sub << 4);
        int flat = ((mf * 32 + c) * 64 + lane_r) * 8 + jj;
        ApHi[flat] = hb;
        ApLo[flat] = lb;
    }
}

// ---------- recurrent GEMM: C[512 x 3x1024] = A @ W^T, B LDS-staged, fused epilogues ----------
template <int EPI>
__global__ __launch_bounds__(512, 2) void k_rnn(const ushort* __restrict__ Ah,
                                                const ushort* __restrict__ Al,
                                                const ushort* __restrict__ Bh,
                                                const ushort* __restrict__ Bl,
                                                const float* __restrict__ bias,
                                                float* __restrict__ outF,
                                                const float* __restrict__ gi_all,
                                                const int* __restrict__ tok,
                                                const float* __restrict__ hOld,
                                                ushort* __restrict__ ApHi,
                                                ushort* __restrict__ ApLo) {
    __shared__ ushort Bs[2][48][512];   // 96 KB: [buf][unit][lane*8]
    int id = blockIdx.x;
    int xcd = id & 7, r = id >> 3;
    int jt = xcd * 4 + (r & 3);         // 0..31 : w panel per XCD stays L2-resident
    int mt = r >> 2;                    // 0..7
    int tid = threadIdx.x, wid = tid >> 6, l = tid & 63;
    int wm = wid >> 1, wj = wid & 1;
    int mf = mt * 4 + wm;               // 0..31
    int jf = jt * 2 + wj;               // 0..63
    int jcol = jf * 16 + (l & 15);

    // epilogue operand prefetch (hidden under the K-loop)
    float giR[4][3], hR[4];
    int bR[4];
    if constexpr (EPI == 1) {
#pragma unroll
        for (int q = 0; q < 4; ++q) {
            bR[q] = mf * 16 + ((l >> 4) << 2) + q;
            int tkq = tok[bR[q]];
            const float* gi = gi_all + (size_t)tkq * 3072;
            giR[q][0] = gi[jcol];
            giR[q][1] = gi[1024 + jcol];
            giR[q][2] = gi[2048 + jcol];
            hR[q] = hOld[(size_t)bR[q] * 1024 + jcol];
        }
    }

    f32x4 acc[3];
#pragma unroll
    for (int g = 0; g < 3; ++g) acc[g] = (f32x4)0.f;

    bf16x8 stg[6], aH0[4], aL0[4], aH1[4], aL1[4];

#define STG_LD(it)                                                                     \
    {                                                                                  \
        _Pragma("unroll") for (int k = 0; k < 6; ++k) {                                \
            int u = wid + 8 * k;                                                       \
            int hl = u & 1, wjb = (u >> 1) & 1, g = (u >> 2) % 3, cu = u / 12;         \
            const ushort* sp = hl ? Bl : Bh;                                           \
            stg[k] = *(const bf16x8*)(sp +                                             \
                (size_t)(((g * 64 + jt * 2 + wjb) * 32 + (it) * 4 + cu) * 64 + l) * 8);\
        }                                                                              \
    }
#define STG_WR(buf)                                                                    \
    {                                                                                  \
        _Pragma("unroll") for (int k = 0; k < 6; ++k)                                  \
            *(bf16x8*)&Bs[buf][wid + 8 * k][l * 8] = stg[k];                           \
    }
#define A_LD(DH, DL, it)                                                               \
    {                                                                                  \
        _Pragma("unroll") for (int cc = 0; cc < 4; ++cc) {                             \
            DH[cc] = *(const bf16x8*)(Ah + (size_t)((mf * 32 + (it) * 4 + cc) * 64 + l) * 8); \
            DL[cc] = *(const bf16x8*)(Al + (size_t)((mf * 32 + (it) * 4 + cc) * 64 + l) * 8); \
        }                                                                              \
    }
#define CMP(buf, AH, AL)                                                               \
    {                                                                                  \
        _Pragma("unroll") for (int cc = 0; cc < 4; ++cc)                               \
            _Pragma("unroll") for (int g = 0; g < 3; ++g) {                            \
                bf16x8 bhh = *(const bf16x8*)&Bs[buf][cc * 12 + g * 4 + wj * 2 + 0][l * 8]; \
                bf16x8 bll = *(const bf16x8*)&Bs[buf][cc * 12 + g * 4 + wj * 2 + 1][l * 8]; \
                acc[g] = __builtin_amdgcn_mfma_f32_16x16x32_bf16(AH[cc], bhh, acc[g], 0, 0, 0); \
                acc[g] = __builtin_amdgcn_mfma_f32_16x16x32_bf16(AH[cc], bll, acc[g], 0, 0, 0); \
                acc[g] = __builtin_amdgcn_mfma_f32_16x16x32_bf16(AL[cc], bhh, acc[g], 0, 0, 0); \
            }                                                                          \
    }

    STG_LD(0)
    STG_WR(0)
    STG_LD(1)
    A_LD(aH0, aL0, 0)
    __syncthreads();
#pragma unroll
    for (int it = 0; it < 8; ++it) {
        int buf = it & 1;
        if (it < 7) STG_WR(buf ^ 1)          // data for it+1 (loaded last iter)
        if (it < 6) STG_LD(it + 2)           // issue loads for it+2
        if (it & 1) {
            if (it < 7) A_LD(aH0, aL0, it + 1)
            CMP(buf, aH1, aL1)
        } else {
            if (it < 7) A_LD(aH1, aL1, it + 1)
            CMP(buf, aH0, aL0)
        }
        __syncthreads();
    }
#undef STG_LD
#undef STG_WR
#undef A_LD
#undef CMP

    if constexpr (EPI == 0) {
#pragma unroll
        for (int q = 0; q < 4; ++q) {
            int b = mf * 16 + ((l >> 4) << 2) + q;
#pragma unroll
            for (int g = 0; g < 3; ++g)
                outF[(size_t)b * 3072 + g * 1024 + jcol] =
                    acc[g][q] + bias[g * 1024 + jcol];
        }
    } else {
        float bj0 = bias[jcol], bj1 = bias[1024 + jcol], bj2 = bias[2048 + jcol];
        int c = jcol >> 5, sub = (jcol >> 3) & 3, jj = jcol & 7;
#pragma unroll
        for (int q = 0; q < 4; ++q) {
            int b = bR[q];
            float rr = sigm(giR[q][0] + acc[0][q] + bj0);
            float zz = sigm(giR[q][1] + acc[1][q] + bj1);
            float nn = tanhf(giR[q][2] + rr * (acc[2][q] + bj2));
            float hv = (1.f - zz) * nn + zz * hR[q];
            outF[(size_t)b * 1024 + jcol] = hv;
            ushort hb = f2bf(hv);
            ushort lb = f2bf(hv - bf2f(hb));
            int lane_r = (b & 15) + (sub << 4);
            int flat = ((mf * 32 + c) * 64 + lane_r) * 8 + jj;
            ApHi[flat] = hb;
            ApLo[flat] = lb;
        }
    }
}

// ---------- logits GEMM [512 x 512 x 1024]: wave per (mf, vf) -> 1024 waves = 256 blocks ----------
__global__ __launch_bounds__(256) void k_lgt(const ushort* __restrict__ Ah,
                                             const ushort* __restrict__ Al,
                                             const ushort* __restrict__ Bh,
                                             const ushort* __restrict__ Bl,
                                             const float* __restrict__ bias,
                                             float* __restrict__ outF) {
    int p = blockIdx.x * 4 + (threadIdx.x >> 6);   // 0..1023
    int l = threadIdx.x & 63;
    int mf = p >> 5, vf = p & 31;                  // mf 0..31, vf 0..31
    size_t ab = (size_t)(mf * 32) * 512 + l * 8;
    size_t bb = (size_t)(vf * 32) * 512 + l * 8;
    f32x4 acc = (f32x4)0.f;
    bf16x8 a0h, a0l, b0h, b0l, a1h, a1l, b1h, b1l;

#define LD1(AH, AL, BH, BL, c)                                                         \
    {                                                                                  \
        AH = *(const bf16x8*)(Ah + ab + (size_t)(c) * 512);                            \
        AL = *(const bf16x8*)(Al + ab + (size_t)(c) * 512);                            \
        BH = *(const bf16x8*)(Bh + bb + (size_t)(c) * 512);                            \
        BL = *(const bf16x8*)(Bl + bb + (size_t)(c) * 512);                            \
    }
#define ST1(AH, AL, BH, BL)                                                            \
    {                                                                                  \
        acc = __builtin_amdgcn_mfma_f32_16x16x32_bf16(AH, BH, acc, 0, 0, 0);           \
        acc = __builtin_amdgcn_mfma_f32_16x16x32_bf16(AH, BL, acc, 0, 0, 0);           \
        acc = __builtin_amdgcn_mfma_f32_16x16x32_bf16(AL, BH, acc, 0, 0, 0);           \
    }

    LD1(a0h, a0l, b0h, b0l, 0)
#pragma unroll
    for (int c = 0; c < 32; c += 2) {
        LD1(a1h, a1l, b1h, b1l, c + 1)
        ST1(a0h, a0l, b0h, b0l)
        if (c + 2 < 32) LD1(a0h, a0l, b0h, b0l, c + 2)
        ST1(a1h, a1l, b1h, b1l)
    }
#undef LD1
#undef ST1

    int v = vf * 16 + (l & 15);
    float bv = bias[v];
#pragma unroll
    for (int q = 0; q < 4; ++q) {
        int b = mf * 16 + ((l >> 4) << 2) + q;
        outF[(size_t)b * Vd + v] = acc[q] + bv;
    }
}

// ---------- wave-per-row argmax (+ log_softmax on last step) ----------
__global__ __launch_bounds__(64) void k_argmax(const float* __restrict__ logits,
                                               int* __restrict__ tok,
                                               float* __restrict__ out_idx,
                                               float* __restrict__ out_lsm,
                                               int do_lsm) {
    int b = blockIdx.x, l = threadIdx.x;
    const float* row = logits + (size_t)b * Vd;
    float bv = -3.4e38f;
    int bi = 0;
#pragma unroll
    for (int s = 0; s < 8; ++s) {
        int v = s * 64 + l;
        float x = row[v];
        if (x > bv) { bv = x; bi = v; }
    }
#pragma unroll
    for (int off = 1; off < 64; off <<= 1) {
        float ov = __shfl_xor(bv, off);
        int oi = __shfl_xor(bi, off);
        if (ov > bv || (ov == bv && oi < bi)) { bv = ov; bi = oi; }
    }
    if (l == 0) {
        tok[b] = bi;
        out_idx[b] = (float)bi;
    }
    if (do_lsm) {
        float sum = 0.f;
#pragma unroll
        for (int s = 0; s < 8; ++s) sum += expf(row[s * 64 + l] - bv);
#pragma unroll
        for (int off = 1; off < 64; off <<= 1) sum += __shfl_xor(sum, off);
        float lse = logf(sum) + bv;
#pragma unroll
        for (int s = 0; s < 8; ++s) {
            int v = s * 64 + l;
            out_lsm[(size_t)b * Vd + v] = row[v] - lse;
        }
    }
}

__global__ void k_init(int* __restrict__ tok, float* __restrict__ out_idx0) {
    int i = blockIdx.x * 64 + threadIdx.x;
    if (i < Bsz) {
        tok[i] = 0;
        out_idx0[i] = 0.f;
    }
}

extern "C" void kernel_launch(void* const* d_in, const int* in_sizes, int n_in,
                              void* d_out, int out_size, void* d_ws, size_t ws_size,
                              hipStream_t stream) {
    const float* sm    = (const float*)d_in[0];
    const float* emb   = (const float*)d_in[1];
    const float* w_ih  = (const float*)d_in[2];
    const float* w_hh  = (const float*)d_in[3];
    const float* b_ih  = (const float*)d_in[4];
    const float* b_hh  = (const float*)d_in[5];
    const float* w_out = (const float*)d_in[6];
    const float* b_out = (const float*)d_in[7];
    const float* cw    = (const float*)d_in[8];
    const float* cb    = (const float*)d_in[9];
    const float* ew    = (const float*)d_in[10];
    const float* eb    = (const float*)d_in[11];

    float* out0 = (float*)d_out;                   // decoder_output  [512,512]
    float* out1 = out0 + (size_t)Bsz * Vd;         // decoder_hidden  [30,512,1024]
    float* out2 = out1 + (size_t)NSTEP * Bsz * Hd; // decoded_indices [31,512]

    const int SMN = Bsz * Ll * Cc;                 // 7864320
    char* wsp = (char*)d_ws;
    float*  f_gi  = (float*)wsp;  wsp += sizeof(float) * Bsz * 3072;
    float*  f_h0  = (float*)wsp;  wsp += sizeof(float) * Bsz * Hd;
    float*  f_log = (float*)wsp;  wsp += sizeof(float) * Bsz * Vd;
    ushort* ApHi0 = (ushort*)wsp; wsp += sizeof(ushort) * Bsz * Hd;
    ushort* ApLo0 = (ushort*)wsp; wsp += sizeof(ushort) * Bsz * Hd;
    ushort* ApHi1 = (ushort*)wsp; wsp += sizeof(ushort) * Bsz * Hd;
    ushort* ApLo1 = (ushort*)wsp; wsp += sizeof(ushort) * Bsz * Hd;
    ushort* embH  = (ushort*)wsp; wsp += sizeof(ushort) * Vd * Hd;
    ushort* embL  = (ushort*)wsp; wsp += sizeof(ushort) * Vd * Hd;
    ushort* wihH  = (ushort*)wsp; wsp += sizeof(ushort) * 3072 * Hd;
    ushort* wihL  = (ushort*)wsp; wsp += sizeof(ushort) * 3072 * Hd;
    ushort* whhH  = (ushort*)wsp; wsp += sizeof(ushort) * 3072 * Hd;
    ushort* whhL  = (ushort*)wsp; wsp += sizeof(ushort) * 3072 * Hd;
    ushort* woutH = (ushort*)wsp; wsp += sizeof(ushort) * Vd * Hd;
    ushort* woutL = (ushort*)wsp; wsp += sizeof(ushort) * Vd * Hd;
    ushort* smH   = (ushort*)wsp; wsp += sizeof(ushort) * (SMN + 32 * Cc);
    ushort* smL   = (ushort*)wsp; wsp += sizeof(ushort) * (SMN + 32 * Cc);
    ushort* cwBH  = (ushort*)wsp; wsp += sizeof(ushort) * 2 * 40 * 64 * 8;
    ushort* cwBL  = (ushort*)wsp; wsp += sizeof(ushort) * 2 * 40 * 64 * 8;
    int*    tok   = (int*)wsp;    wsp += sizeof(int) * Bsz;

    // one-time setup
    k_split<<<SMN / 256, 256, 0, stream>>>(sm, smH, smL, SMN);
    k_packconv<<<160, 256, 0, stream>>>(cw, cwBH, cwBL);
    k_pack<<<(3072 * 1024) / 256, 256, 0, stream>>>(w_ih, wihH, wihL, 3072 * 1024);
    k_pack<<<(3072 * 1024) / 256, 256, 0, stream>>>(w_hh, whhH, whhL, 3072 * 1024);
    k_pack<<<(512 * 1024) / 256, 256, 0, stream>>>(w_out, woutH, woutL, 512 * 1024);
    k_pack<<<(512 * 1024) / 256, 256, 0, stream>>>(emb, embH, embL, 512 * 1024);
    k_convmfma<<<Bsz, 256, 0, stream>>>(smH, smL, cwBH, cwBL, cb, ew, eb,
                                        f_h0, ApHi0, ApLo0);
    // gi table: emb @ w_ih^T + b_ih for all 512 tokens
    k_rnn<0><<<256, 512, 0, stream>>>(embH, embL, wihH, wihL, b_ih, f_gi,
                                      nullptr, nullptr, nullptr, nullptr, nullptr);
    k_init<<<8, 64, 0, stream>>>(tok, out2);

    ushort* aH[2] = {ApHi0, ApHi1};
    ushort* aL[2] = {ApLo0, ApLo1};
    for (int t = 0; t < NSTEP; ++t) {
        int cur = t & 1, nxt = cur ^ 1;
        const float* hOld = (t == 0) ? f_h0 : (out1 + (size_t)(t - 1) * Bsz * Hd);
        k_rnn<1><<<256, 512, 0, stream>>>(
            aH[cur], aL[cur], whhH, whhL, b_hh, out1 + (size_t)t * Bsz * Hd,
            f_gi, tok, hOld, aH[nxt], aL[nxt]);
        k_lgt<<<256, 256, 0, stream>>>(aH[nxt], aL[nxt], woutH, woutL, b_out, f_log);
        k_argmax<<<Bsz, 64, 0, stream>>>(f_log, tok, out2 + (size_t)(t + 1) * Bsz,
                                         out0, t == NSTEP - 1 ? 1 : 0);
    }
}